// Round 3
// baseline (291.944 us; speedup 1.0000x reference)
//
#include <hip/hip_runtime.h>

#define TSTEPS 2048
#define BATCH  4096
#define HID    4
#define NLAYER 3
#define STRIDE (BATCH*HID)   // 16384 floats per timestep slab
#define PF     8             // prefetch depth (register queue)

// Broadcast component k (0..3) to all 4 lanes of each quad via DPP quad_perm.
// dpp_ctrl = k in all four 2-bit slots = k*0x55. Full row/bank masks.
#define QB(v,k) __int_as_float(__builtin_amdgcn_update_dpp( \
    0, __float_as_int(v), (k)*0x55, 0xF, 0xF, true))

__device__ __forceinline__ float fast_exp2(float x) {
#if __has_builtin(__builtin_amdgcn_exp2f)
  return __builtin_amdgcn_exp2f(x);
#else
  return exp2f(x);
#endif
}

__device__ __forceinline__ float fast_rcp(float x) {
#if __has_builtin(__builtin_amdgcn_rcpf)
  return __builtin_amdgcn_rcpf(x);
#else
  return 1.0f / x;
#endif
}

// acc is already scaled by K = 2*log2(e):  tanh(a) = 1 - 2/(1 + exp2(K*a))
__device__ __forceinline__ float actv(float acc) {
  float e = fast_exp2(acc);
  float r = fast_rcp(e + 1.0f);
  return fmaf(-2.0f, r, 1.0f);
}

__global__ __launch_bounds__(64) void rnn_scan(
    const float* __restrict__ X,    // (T, B, H)
    const float* __restrict__ H0,   // (L, B, H)
    const float* __restrict__ Wih,  // (L, H, H)
    const float* __restrict__ Whh,  // (L, H, H)
    const float* __restrict__ bih,  // (L, H)
    const float* __restrict__ bhh,  // (L, H)
    float* __restrict__ Y)          // (T, B, H)
{
  const int tid = blockIdx.x * 64 + threadIdx.x;  // 0..16383
  const int j   = tid & 3;                        // hidden component owned
  const float K = 2.8853900817779268f;            // 2*log2(e)

  // Per-thread weight rows (row j of each W), pre-scaled by K so the
  // matvec accumulator is directly the exp2 argument.
  float wi[NLAYER][HID], wh[NLAYER][HID], bs[NLAYER];
#pragma unroll
  for (int l = 0; l < NLAYER; ++l) {
#pragma unroll
    for (int k = 0; k < HID; ++k) {
      wi[l][k] = Wih[(l*HID + j)*HID + k] * K;
      wh[l][k] = Whh[(l*HID + j)*HID + k] * K;
    }
    bs[l] = (bih[l*HID + j] + bhh[l*HID + j]) * K;
  }

  float h1 = H0[0*STRIDE + tid];
  float h2 = H0[1*STRIDE + tid];
  float h3 = H0[2*STRIDE + tid];

  const float* __restrict__ xp = X + tid;
  float* __restrict__ yp = Y + tid;

  // Software prefetch queue, statically indexed (fully unrolled).
  float q[PF];
#pragma unroll
  for (int u = 0; u < PF; ++u) q[u] = xp[(size_t)u * STRIDE];

  for (int t = 0; t < TSTEPS; t += PF) {
#pragma unroll
    for (int u = 0; u < PF; ++u) {
      const float xc = q[u];
      // issue prefetch PF steps ahead (clamped; tail loads are unused)
      int tn = t + PF + u;
      tn = (tn > TSTEPS - 1) ? (TSTEPS - 1) : tn;
      q[u] = xp[(size_t)tn * STRIDE];

      // ---- layer 1: input xc, state h1 ----
      float a1 = bs[0];
      a1 = fmaf(QB(xc, 0), wi[0][0], a1);
      a1 = fmaf(QB(xc, 1), wi[0][1], a1);
      a1 = fmaf(QB(xc, 2), wi[0][2], a1);
      a1 = fmaf(QB(xc, 3), wi[0][3], a1);
      a1 = fmaf(QB(h1, 0), wh[0][0], a1);
      a1 = fmaf(QB(h1, 1), wh[0][1], a1);
      a1 = fmaf(QB(h1, 2), wh[0][2], a1);
      a1 = fmaf(QB(h1, 3), wh[0][3], a1);
      h1 = actv(a1);

      // ---- layer 2: input h1, state h2 ----
      float a2 = bs[1];
      a2 = fmaf(QB(h1, 0), wi[1][0], a2);
      a2 = fmaf(QB(h1, 1), wi[1][1], a2);
      a2 = fmaf(QB(h1, 2), wi[1][2], a2);
      a2 = fmaf(QB(h1, 3), wi[1][3], a2);
      a2 = fmaf(QB(h2, 0), wh[1][0], a2);
      a2 = fmaf(QB(h2, 1), wh[1][1], a2);
      a2 = fmaf(QB(h2, 2), wh[1][2], a2);
      a2 = fmaf(QB(h2, 3), wh[1][3], a2);
      h2 = actv(a2);

      // ---- layer 3: input h2, state h3 ----
      float a3 = bs[2];
      a3 = fmaf(QB(h2, 0), wi[2][0], a3);
      a3 = fmaf(QB(h2, 1), wi[2][1], a3);
      a3 = fmaf(QB(h2, 2), wi[2][2], a3);
      a3 = fmaf(QB(h2, 3), wi[2][3], a3);
      a3 = fmaf(QB(h3, 0), wh[2][0], a3);
      a3 = fmaf(QB(h3, 1), wh[2][1], a3);
      a3 = fmaf(QB(h3, 2), wh[2][2], a3);
      a3 = fmaf(QB(h3, 3), wh[2][3], a3);
      h3 = actv(a3);

      yp[(size_t)(t + u) * STRIDE] = h3;
    }
  }
}

extern "C" void kernel_launch(void* const* d_in, const int* in_sizes, int n_in,
                              void* d_out, int out_size, void* d_ws, size_t ws_size,
                              hipStream_t stream) {
  const float* X   = (const float*)d_in[0];
  const float* H0  = (const float*)d_in[1];
  const float* Wih = (const float*)d_in[2];
  const float* Whh = (const float*)d_in[3];
  const float* bih = (const float*)d_in[4];
  const float* bhh = (const float*)d_in[5];
  float* Y = (float*)d_out;

  // 16384 threads: one per (batch, hidden-component). One wave per block,
  // 256 blocks -> one wave on each of the 256 CUs.
  rnn_scan<<<dim3(STRIDE / 64), dim3(64), 0, stream>>>(X, H0, Wih, Whh, bih, bhh, Y);
}

// Round 5
// 281.110 us; speedup vs baseline: 1.0385x; 1.0385x over previous
//
#include <hip/hip_runtime.h>

#define TSTEPS 2048
#define BATCH  4096
#define HID    4
#define NLAYER 3
#define STRIDE (BATCH*HID)   // 16384 floats per timestep slab
#define PF     8             // prefetch ring depth

// Broadcast component k (0..3) to all 4 lanes of each quad via DPP quad_perm.
#define QB(v,k) __int_as_float(__builtin_amdgcn_update_dpp( \
    0, __float_as_int(v), (k)*0x55, 0xF, 0xF, true))

__device__ __forceinline__ float fast_exp2(float x) {
#if __has_builtin(__builtin_amdgcn_exp2f)
  return __builtin_amdgcn_exp2f(x);
#else
  return exp2f(x);
#endif
}
__device__ __forceinline__ float fast_rcp(float x) {
#if __has_builtin(__builtin_amdgcn_rcpf)
  return __builtin_amdgcn_rcpf(x);
#else
  return 1.0f / x;
#endif
}

// Weights pre-scaled by K = 2*log2(e):  tanh(a) = 1 - 2/(1 + exp2(K*a))
__device__ __forceinline__ float actv(float acc) {
  float e = fast_exp2(acc);
  float r = fast_rcp(e + 1.0f);
  return fmaf(-2.0f, r, 1.0f);
}

// One RNN layer step for this lane's component: two parallel 4-FMA chains.
__device__ __forceinline__ float layer_step(const float* __restrict__ wi,
                                            const float* __restrict__ wh,
                                            float b, float vin, float hprev) {
  float ai = b;
  ai = fmaf(QB(vin, 0), wi[0], ai);
  ai = fmaf(QB(vin, 1), wi[1], ai);
  ai = fmaf(QB(vin, 2), wi[2], ai);
  ai = fmaf(QB(vin, 3), wi[3], ai);
  float ah;
  ah =      QB(hprev, 0) * wh[0];
  ah = fmaf(QB(hprev, 1), wh[1], ah);
  ah = fmaf(QB(hprev, 2), wh[2], ah);
  ah = fmaf(QB(hprev, 3), wh[3], ah);
  return actv(ai + ah);
}

__global__ __launch_bounds__(64) void rnn_scan(
    const float* __restrict__ X,    // (T, B, H)
    const float* __restrict__ H0,   // (L, B, H)
    const float* __restrict__ Wih,  // (L, H, H)
    const float* __restrict__ Whh,  // (L, H, H)
    const float* __restrict__ bih,  // (L, H)
    const float* __restrict__ bhh,  // (L, H)
    float* __restrict__ Y)          // (T, B, H)
{
  const int tid = blockIdx.x * 64 + threadIdx.x;  // 0..16383
  const int j   = tid & 3;                        // hidden component owned
  const float K = 2.8853900817779268f;            // 2*log2(e)

  float wi[NLAYER][HID], wh[NLAYER][HID], bs[NLAYER];
#pragma unroll
  for (int l = 0; l < NLAYER; ++l) {
#pragma unroll
    for (int k = 0; k < HID; ++k) {
      wi[l][k] = Wih[(l*HID + j)*HID + k] * K;
      wh[l][k] = Whh[(l*HID + j)*HID + k] * K;
    }
    bs[l] = (bih[l*HID + j] + bhh[l*HID + j]) * K;
  }

  float h1 = H0[0*STRIDE + tid];
  float h2 = H0[1*STRIDE + tid];
  float h3 = H0[2*STRIDE + tid];

  const float* __restrict__ xp = X + tid;
  float* __restrict__ yp = Y + tid;

  // Direct loads for the two prologue steps (latency overlaps weight setup).
  float x0 = xp[(size_t)0 * STRIDE];
  float x1 = xp[(size_t)1 * STRIDE];

  // Prefetch ring for the main loop: q[u] holds x@(2 + u) initially;
  // slot for iteration i is (i-2)&7 (static under unroll-8).
  float q[PF];
#pragma unroll
  for (int u = 0; u < PF; ++u) q[u] = xp[(size_t)(2 + u) * STRIDE];

  // ---- prologue: fill the layer pipeline ----
  // iter 0: h1@0
  h1 = layer_step(wi[0], wh[0], bs[0], x0, h1);
  // iter 1: h1@1, h2@0
  {
    float h1n = layer_step(wi[0], wh[0], bs[0], x1, h1);
    float h2n = layer_step(wi[1], wh[1], bs[1], h1, h2);
    h1 = h1n; h2 = h2n;
  }

  // ---- main loop: iterations i = 2 .. 2041 (255 x unroll-8) ----
  // Entering iter i: h1 = h1@(i-1), h2 = h2@(i-2), h3 = h3@(i-3).
  // Computes h1@i, h2@(i-1), h3@(i-2); stores Y[i-2]. All three layer
  // computations depend only on iteration-start values -> 3-way ILP.
  for (int io = 0; io < (TSTEPS - 2) / PF; ++io) {
#pragma unroll
    for (int u = 0; u < PF; ++u) {
      const int i = 2 + io * PF + u;
      const float xc = q[u];
      int tn = i + PF; tn = (tn > TSTEPS - 1) ? (TSTEPS - 1) : tn;
      q[u] = xp[(size_t)tn * STRIDE];

      float h1n = layer_step(wi[0], wh[0], bs[0], xc, h1);
      float h2n = layer_step(wi[1], wh[1], bs[1], h1, h2);
      float h3n = layer_step(wi[2], wh[2], bs[2], h2, h3);
      yp[(size_t)(i - 2) * STRIDE] = h3n;
      h1 = h1n; h2 = h2n; h3 = h3n;
    }
  }

  // ---- static tail: iterations i = 2042 .. 2047 (ring slots 0..5) ----
#pragma unroll
  for (int u = 0; u < 6; ++u) {
    const int i = 2042 + u;
    const float xc = q[u];
    float h1n = layer_step(wi[0], wh[0], bs[0], xc, h1);
    float h2n = layer_step(wi[1], wh[1], bs[1], h1, h2);
    float h3n = layer_step(wi[2], wh[2], bs[2], h2, h3);
    yp[(size_t)(i - 2) * STRIDE] = h3n;
    h1 = h1n; h2 = h2n; h3 = h3n;
  }

  // ---- epilogue: drain the pipeline ----
  // iter 2048: h2@2047, h3@2046
  {
    float h2n = layer_step(wi[1], wh[1], bs[1], h1, h2);
    float h3n = layer_step(wi[2], wh[2], bs[2], h2, h3);
    yp[(size_t)2046 * STRIDE] = h3n;
    h2 = h2n; h3 = h3n;
  }
  // iter 2049: h3@2047
  {
    float h3n = layer_step(wi[2], wh[2], bs[2], h2, h3);
    yp[(size_t)2047 * STRIDE] = h3n;
  }
}

extern "C" void kernel_launch(void* const* d_in, const int* in_sizes, int n_in,
                              void* d_out, int out_size, void* d_ws, size_t ws_size,
                              hipStream_t stream) {
  const float* X   = (const float*)d_in[0];
  const float* H0  = (const float*)d_in[1];
  const float* Wih = (const float*)d_in[2];
  const float* Whh = (const float*)d_in[3];
  const float* bih = (const float*)d_in[4];
  const float* bhh = (const float*)d_in[5];
  float* Y = (float*)d_out;

  rnn_scan<<<dim3(STRIDE / 64), dim3(64), 0, stream>>>(X, H0, Wih, Whh, bih, bhh, Y);
}